// Round 1
// baseline (728.238 us; speedup 1.0000x reference)
//
#include <hip/hip_runtime.h>
#include <hip/hip_bf16.h>

#define TT 2048
#define HH 1024
#define FF 4096
#define NE 8

#define BM1 256
#define BN1 128
#define BM2 128
#define BN2 128
#define BK  32
#define LDK 40   // BK + 8 bf16 pad -> row stride 80B (16B-aligned, ~2-way banks)

typedef __attribute__((ext_vector_type(4))) float f4;
typedef __attribute__((ext_vector_type(4))) short s4;
typedef __attribute__((ext_vector_type(8))) short s8;

static __device__ __forceinline__ short f2bf(float x) {
  union { __hip_bfloat16 b; short s; } u;
  u.b = __float2bfloat16(x);
  return u.s;
}

// ---------------- Router: logits -> softcap -> softmax -> top2 -> expert lists
__global__ __launch_bounds__(256) void k_router(
    const float* __restrict__ h, const float* __restrict__ gw,
    int* __restrict__ cnt, int* __restrict__ tok, float* __restrict__ wt)
{
  const int lane = threadIdx.x & 63;
  const int wid  = threadIdx.x >> 6;
  const int t = blockIdx.x * 4 + wid;
  const float* hr = h + (size_t)t * HH;

  float acc[NE];
#pragma unroll
  for (int e = 0; e < NE; e++) acc[e] = 0.f;
#pragma unroll 4
  for (int i = 0; i < HH / 64; i++) {
    float hv = hr[lane + (i << 6)];
#pragma unroll
    for (int e = 0; e < NE; e++) acc[e] += hv * gw[e * HH + lane + (i << 6)];
  }
#pragma unroll
  for (int e = 0; e < NE; e++) {
    float v = acc[e];
#pragma unroll
    for (int s = 32; s > 0; s >>= 1) v += __shfl_xor(v, s);
    acc[e] = v;
  }
  if (lane == 0) {
    float p[NE];
    float m = -1e30f;
#pragma unroll
    for (int e = 0; e < NE; e++) {
      p[e] = 30.f * tanhf(acc[e] * (1.f / 30.f));
      m = fmaxf(m, p[e]);
    }
    float s = 0.f;
#pragma unroll
    for (int e = 0; e < NE; e++) { p[e] = expf(p[e] - m); s += p[e]; }
    const float inv = 1.f / s;
    int e1 = 0;
#pragma unroll
    for (int e = 1; e < NE; e++) if (p[e] > p[e1]) e1 = e;
    int e2 = (e1 == 0) ? 1 : 0;
#pragma unroll
    for (int e = 0; e < NE; e++) if (e != e1 && p[e] > p[e2]) e2 = e;

    int pos1 = atomicAdd(&cnt[e1], 1);
    tok[e1 * TT + pos1] = t;
    wt [e1 * TT + pos1] = p[e1] * inv;
    int pos2 = atomicAdd(&cnt[e2], 1);
    tok[e2 * TT + pos2] = t;
    wt [e2 * TT + pos2] = p[e2] * inv;
  }
}

// ---------------- FFN1: act[slot,f] = gelu(x@W1^T) * (x@W3^T)  (gathered rows)
__global__ __launch_bounds__(512) void k_ffn1(
    const float* __restrict__ h, const float* __restrict__ w1,
    const float* __restrict__ w3, const int* __restrict__ cnt,
    const int* __restrict__ tok, __hip_bfloat16* __restrict__ act)
{
  const int e  = blockIdx.z;
  const int mt = blockIdx.y;
  const int nt = blockIdx.x;
  const int ce = cnt[e];
  if (mt * BM1 >= ce) return;
  int base = 0;
  for (int i = 0; i < e; i++) base += cnt[i];

  __shared__ short As [BM1][LDK];
  __shared__ short B1s[BN1][LDK];
  __shared__ short B3s[BN1][LDK];

  const int tid  = threadIdx.x;
  const int lane = tid & 63;
  const int wid  = tid >> 6;
  const int wm   = wid >> 1;   // 0..3 -> 64 rows each
  const int wn   = wid & 1;    // 0..1 -> 64 cols each

  const int ar = tid >> 3;          // 0..63
  const int ac = (tid & 7) << 2;    // 0,4,..28

  const float* ap[4];
#pragma unroll
  for (int p = 0; p < 4; p++) {
    int pos = mt * BM1 + p * 64 + ar;
    int tk = tok[e * TT + ((pos < ce) ? pos : 0)];
    ap[p] = h + (size_t)tk * HH + ac;
  }
  const float* b1p[2];
  const float* b3p[2];
#pragma unroll
  for (int p = 0; p < 2; p++) {
    int fr = nt * BN1 + p * 64 + ar;
    b1p[p] = w1 + ((size_t)e * FF + fr) * HH + ac;
    b3p[p] = w3 + ((size_t)e * FF + fr) * HH + ac;
  }

  f4 accg[4][4], accu[4][4];
#pragma unroll
  for (int i = 0; i < 4; i++)
#pragma unroll
    for (int j = 0; j < 4; j++) {
      f4 z = {0.f, 0.f, 0.f, 0.f};
      accg[i][j] = z; accu[i][j] = z;
    }

  for (int kk = 0; kk < HH; kk += BK) {
#pragma unroll
    for (int p = 0; p < 4; p++) {
      f4 v = *(const f4*)(ap[p] + kk);
      s4 b = { f2bf(v.x), f2bf(v.y), f2bf(v.z), f2bf(v.w) };
      *(s4*)&As[p * 64 + ar][ac] = b;
    }
#pragma unroll
    for (int p = 0; p < 2; p++) {
      f4 v = *(const f4*)(b1p[p] + kk);
      s4 b = { f2bf(v.x), f2bf(v.y), f2bf(v.z), f2bf(v.w) };
      *(s4*)&B1s[p * 64 + ar][ac] = b;
      f4 w = *(const f4*)(b3p[p] + kk);
      s4 c = { f2bf(w.x), f2bf(w.y), f2bf(w.z), f2bf(w.w) };
      *(s4*)&B3s[p * 64 + ar][ac] = c;
    }
    __syncthreads();

    s8 af[4], b1f[4], b3f[4];
    const int fr = lane & 15;
    const int fk = (lane >> 4) << 3;
#pragma unroll
    for (int i = 0; i < 4; i++) {
      af [i] = *(const s8*)&As [wm * 64 + i * 16 + fr][fk];
      b1f[i] = *(const s8*)&B1s[wn * 64 + i * 16 + fr][fk];
      b3f[i] = *(const s8*)&B3s[wn * 64 + i * 16 + fr][fk];
    }
#pragma unroll
    for (int i = 0; i < 4; i++)
#pragma unroll
      for (int j = 0; j < 4; j++) {
        accg[i][j] = __builtin_amdgcn_mfma_f32_16x16x32_bf16(af[i], b1f[j], accg[i][j], 0, 0, 0);
        accu[i][j] = __builtin_amdgcn_mfma_f32_16x16x32_bf16(af[i], b3f[j], accu[i][j], 0, 0, 0);
      }
    __syncthreads();
  }

#pragma unroll
  for (int i = 0; i < 4; i++)
#pragma unroll
    for (int j = 0; j < 4; j++)
#pragma unroll
      for (int r = 0; r < 4; r++) {
        int rr = mt * BM1 + wm * 64 + i * 16 + ((lane >> 4) << 2) + r;
        if (rr < ce) {
          float g = accg[i][j][r];
          float u = accu[i][j][r];
          float a = 0.5f * g * (1.f + erff(g * 0.70710678118f)) * u;
          act[(size_t)(base + rr) * FF + nt * BN1 + wn * 64 + j * 16 + (lane & 15)] =
              __float2bfloat16(a);
        }
      }
}

// ---------------- FFN2: out[tok,h] += wt * (act @ W2^T)
__global__ __launch_bounds__(256) void k_ffn2(
    const __hip_bfloat16* __restrict__ act, const float* __restrict__ w2,
    const int* __restrict__ cnt, const int* __restrict__ tok,
    const float* __restrict__ wt, float* __restrict__ out)
{
  const int e  = blockIdx.z;
  const int mt = blockIdx.y;
  const int nt = blockIdx.x;
  const int ce = cnt[e];
  if (mt * BM2 >= ce) return;
  int base = 0;
  for (int i = 0; i < e; i++) base += cnt[i];

  __shared__ short As[BM2][LDK];
  __shared__ short Bs[BN2][LDK];

  const int tid  = threadIdx.x;   // 256
  const int lane = tid & 63;
  const int wid  = tid >> 6;      // 0..3
  const int wm   = wid >> 1;      // 0..1
  const int wn   = wid & 1;       // 0..1

  const __hip_bfloat16* apt[2];
#pragma unroll
  for (int p = 0; p < 2; p++) {
    int row = mt * BM2 + p * 64 + (tid >> 2);
    int rc = (row < ce) ? row : (ce - 1);
    apt[p] = act + (size_t)(base + rc) * FF + ((tid & 3) << 3);
  }
  const float* bp[4];
#pragma unroll
  for (int p = 0; p < 4; p++) {
    int hr = nt * BN2 + p * 32 + (tid >> 3);
    bp[p] = w2 + ((size_t)e * HH + hr) * FF + ((tid & 7) << 2);
  }

  f4 acc[4][4];
#pragma unroll
  for (int i = 0; i < 4; i++)
#pragma unroll
    for (int j = 0; j < 4; j++) {
      f4 z = {0.f, 0.f, 0.f, 0.f};
      acc[i][j] = z;
    }

  for (int kk = 0; kk < FF; kk += BK) {
#pragma unroll
    for (int p = 0; p < 2; p++) {
      s8 v = *(const s8*)(apt[p] + kk);
      *(s8*)&As[p * 64 + (tid >> 2)][(tid & 3) << 3] = v;
    }
#pragma unroll
    for (int p = 0; p < 4; p++) {
      f4 v = *(const f4*)(bp[p] + kk);
      s4 b = { f2bf(v.x), f2bf(v.y), f2bf(v.z), f2bf(v.w) };
      *(s4*)&Bs[p * 32 + (tid >> 3)][(tid & 7) << 2] = b;
    }
    __syncthreads();

    s8 af[4], bfr[4];
    const int fr = lane & 15;
    const int fk = (lane >> 4) << 3;
#pragma unroll
    for (int i = 0; i < 4; i++) {
      af [i] = *(const s8*)&As[wm * 64 + i * 16 + fr][fk];
      bfr[i] = *(const s8*)&Bs[wn * 64 + i * 16 + fr][fk];
    }
#pragma unroll
    for (int i = 0; i < 4; i++)
#pragma unroll
      for (int j = 0; j < 4; j++)
        acc[i][j] = __builtin_amdgcn_mfma_f32_16x16x32_bf16(af[i], bfr[j], acc[i][j], 0, 0, 0);
    __syncthreads();
  }

#pragma unroll
  for (int i = 0; i < 4; i++)
#pragma unroll
    for (int j = 0; j < 4; j++)
#pragma unroll
      for (int r = 0; r < 4; r++) {
        int rr = mt * BM2 + wm * 64 + i * 16 + ((lane >> 4) << 2) + r;
        if (rr < ce) {
          int   tkn = tok[e * TT + rr];
          float w   = wt [e * TT + rr];
          atomicAdd(&out[(size_t)tkn * HH + nt * BN2 + wn * 64 + j * 16 + (lane & 15)],
                    acc[i][j][r] * w);
        }
      }
}

extern "C" void kernel_launch(void* const* d_in, const int* in_sizes, int n_in,
                              void* d_out, int out_size, void* d_ws, size_t ws_size,
                              hipStream_t stream)
{
  (void)in_sizes; (void)n_in; (void)ws_size;
  const float* h  = (const float*)d_in[0];
  const float* gw = (const float*)d_in[1];
  const float* w1 = (const float*)d_in[2];
  const float* w2 = (const float*)d_in[3];
  const float* w3 = (const float*)d_in[4];
  float* out = (float*)d_out;

  char* ws = (char*)d_ws;
  int*   cnt = (int*)ws;                           // 8 ints
  int*   tok = (int*)(ws + 1024);                  // 8*2048 ints (64 KB)
  float* wtp = (float*)(ws + 1024 + 65536);        // 8*2048 floats (64 KB)
  __hip_bfloat16* act = (__hip_bfloat16*)(ws + 262144);  // 4096*4096 bf16 (32 MB)

  hipMemsetAsync(cnt, 0, 32, stream);
  hipMemsetAsync(d_out, 0, (size_t)out_size * sizeof(float), stream);

  k_router<<<dim3(TT / 4), dim3(256), 0, stream>>>(h, gw, cnt, tok, wtp);
  k_ffn1<<<dim3(FF / BN1, 8, NE), dim3(512), 0, stream>>>(h, w1, w3, cnt, tok, act);
  k_ffn2<<<dim3(HH / BN2, 16, NE), dim3(256), 0, stream>>>(act, w2, cnt, tok, wtp, out);
}